// Round 9
// baseline (229.892 us; speedup 1.0000x reference)
//
#include <hip/hip_runtime.h>
#include <hip/hip_bf16.h>
#include <math.h>

#define N_   16
#define CIN  16
#define D_   32
#define H_   64
#define W_   64
#define COUT 32

#define DHW_ (D_ * H_ * W_)
#define HW_  (H_ * W_)

using frag  = __attribute__((ext_vector_type(8))) short;   // 8 bf16 = 4 VGPRs
using v16f  = __attribute__((ext_vector_type(16))) float;  // MFMA 32x32 accum

static __device__ __forceinline__ unsigned short f2bf(float f) {
  union { float f; unsigned u; } a; a.f = f;
  unsigned u = a.u;
  unsigned r = (u + 0x7fffu + ((u >> 16) & 1u)) >> 16;   // RNE
  return (unsigned short)r;
}
// Packed f32x2 -> bf16x2 (RNE), single HW instruction.
static __device__ __forceinline__ unsigned pack2(float lo, float hi) {
  unsigned r;
  asm("v_cvt_pk_bf16_f32 %0, %1, %2" : "=v"(r) : "v"(lo), "v"(hi));
  return r;
}

// Single fused kernel: conv3d(16->32,k3,p1) + bias + maxpool2^3 + LSE(ch) + relu.
// Block = 4 waves. Grid (wt=2, hpt=8, z=32: n=z>>1, dphalf=z&1).
// R8 vs R7 (96.6us dispatch): VGPR_Count=108 proved the compiler SANK the
// issue() loads past the MFMA block into commit() (pf needs 48 VGPR live;
// 108 < acc64+pf48+frags). The gather's ~900cy HBM latency thus sat inside
// the syncA..syncB critical section every dpi -- the measured stall floor.
// Fix: __builtin_amdgcn_sched_barrier(0) after issue() pins the loads
// before the MFMA block; they land during compute. LDS caps occupancy at
// 2 blocks/CU, so the extra ~60-80 VGPR of live pf state is free.
__global__ __launch_bounds__(256, 2)
void conv_fused(const float* __restrict__ x,
                const float* __restrict__ w,
                const float* __restrict__ bias,
                float* __restrict__ out) {
  // [4 slot][10 row][2 ichalf][34 wslot][8 ic]  = 21760 shorts = 43520 B
  __shared__ __hip_bfloat16 xlds[4 * 10 * 2 * 34 * 8];
  // [27 tap][2 ichalf][32 oc][8 ic]             = 13824 shorts = 27648 B
  __shared__ __hip_bfloat16 wlds[27 * 2 * 32 * 8];

  const int tid = threadIdx.x;
  const int lane = tid & 63;
  const int q = tid >> 6;            // wave id
  const int m = lane & 31;
  const int hs = lane >> 5;
  const int wt = blockIdx.x;         // 0..1
  const int hpt = blockIdx.y;        // 0..7
  const int n = blockIdx.z >> 1;
  const int dphalf = blockIdx.z & 1;

  // ---- stage weights: wlds[tap][ic>>3][oc][ic&7] <- bf16(w[oc][ic][tap]) ----
  for (int i = tid; i < 27 * 32 * 16; i += 256) {
    int ic = i & 15;
    int t2 = i >> 4;
    int oc = t2 & 31;
    int tap = t2 >> 5;
    wlds[((tap * 2 + (ic >> 3)) * 32 + oc) * 8 + (ic & 7)] =
        __hip_bfloat16(__hip_bfloat16_raw{f2bf(w[(oc * 16 + ic) * 27 + tap])});
  }

  // Per-lane bias for the 16 accum rows (row/oc = (r&3)+8*(r>>2)+4*hs).
  float bias_r[16];
  #pragma unroll
  for (int r = 0; r < 16; ++r)
    bias_r[r] = bias[(r & 3) + 8 * (r >> 2) + 4 * hs];

  const int h0 = 8 * hpt - 1;
  const int w0g = wt * 32 - 1;
  const float* xn = x + (size_t)n * CIN * DHW_;

  // 8 uniform channel-base pointers -> SGPR pairs.
  const float* xj[8];
  #pragma unroll
  for (int j = 0; j < 8; ++j) xj[j] = xn + (size_t)j * DHW_;

  // ---- per-thread staging descriptors (decode hoisted out of the dpi loop) --
  // Task t = tid + 256k, t in [0,1360): ru = t/68, sub = t%68,
  // s = sub>>1 (w-slot 0..33), half = sub&1 (ic half), go = (ru>=10),
  // rr = ru%10 (LDS row). Only k=5 can be inactive (t>=1360 <=> tid>=80).
  int goffw[6];   // global word offset, excluding the g-plane term
  int ldsoB[6];   // LDS byte offset within one plane slot
  int go6[6];     // plane offset within the staged pair (0/1)
  bool vhw6[6];   // active && h,w in bounds (g checked per call)
  #pragma unroll
  for (int k = 0; k < 6; ++k) {
    int t = tid + 256 * k;
    int ru = t / 68;
    int sub = t - ru * 68;
    int go = (ru >= 10) ? 1 : 0;
    int rr = ru - 10 * go;
    int s = sub >> 1, half = sub & 1;
    int h = h0 + rr, gw = w0g + s;
    go6[k] = go;
    vhw6[k] = (t < 1360) && ((unsigned)h < (unsigned)H_) &&
              ((unsigned)gw < (unsigned)W_);
    // [row][half][wslot][8ic] bf16 -> byte = ((rr*2 + half)*34 + s)*16
    ldsoB[k] = ((rr * 2 + half) * 34 + s) * 16;
    goffw[k] = half * 8 * DHW_ + h * W_ + gw;
  }
  const bool act5 = (tid < 80);   // k=5 task-active mask (k<5 always active)

  // Immediate staging of planes {g0, g0+1} (prologue): load+pack+write.
  auto stage_now = [&](int g0) {
    #pragma unroll
    for (int k = 0; k < 6; ++k) {
      int g = g0 + go6[k];
      bool v = vhw6[k] && ((unsigned)g < (unsigned)D_);
      unsigned offw = v ? (unsigned)(goffw[k] + g * HW_) : 0u;  // clamp: in-bounds
      float f[8];
      #pragma unroll
      for (int j = 0; j < 8; ++j) f[j] = xj[j][offw];
      uint4 val;
      val.x = v ? pack2(f[0], f[1]) : 0u;
      val.y = v ? pack2(f[2], f[3]) : 0u;
      val.z = v ? pack2(f[4], f[5]) : 0u;
      val.w = v ? pack2(f[6], f[7]) : 0u;
      if (k < 5 || act5)
        *(uint4*)((char*)xlds + ((g & 3) * 10880 + ldsoB[k])) = val;
    }
  };

  float pf[6][8];   // prefetch buffer, live across the MFMA block

  auto issue = [&](int g0) {
    #pragma unroll
    for (int k = 0; k < 6; ++k) {
      int g = g0 + go6[k];
      bool v = vhw6[k] && ((unsigned)g < (unsigned)D_);
      unsigned offw = v ? (unsigned)(goffw[k] + g * HW_) : 0u;
      #pragma unroll
      for (int j = 0; j < 8; ++j) pf[k][j] = xj[j][offw];
    }
  };

  auto commit = [&](int g0) {
    #pragma unroll
    for (int k = 0; k < 6; ++k) {
      int g = g0 + go6[k];
      bool v = vhw6[k] && ((unsigned)g < (unsigned)D_);
      uint4 val;
      val.x = v ? pack2(pf[k][0], pf[k][1]) : 0u;
      val.y = v ? pack2(pf[k][2], pf[k][3]) : 0u;
      val.z = v ? pack2(pf[k][4], pf[k][5]) : 0u;
      val.w = v ? pack2(pf[k][6], pf[k][7]) : 0u;
      if (k < 5 || act5)
        *(uint4*)((char*)xlds + ((g & 3) * 10880 + ldsoB[k])) = val;
    }
  };

  const int dp0 = dphalf * 8;
  stage_now(2 * dp0 - 1);
  stage_now(2 * dp0 + 1);
  __syncthreads();   // prologue staging + weights visible

  for (int dpi = 0; dpi < 8; ++dpi) {
    const int dp = dp0 + dpi;

    if (dpi < 7) issue(2 * dp + 3);   // loads in flight during compute
    // Pin the loads HERE: nothing may cross this fence, so the gather
    // cannot be sunk into commit() (R7's silent failure mode; VGPR=108
    // proved pf never stayed live). Loads now land under the MFMA block.
    __builtin_amdgcn_sched_barrier(0);

    // ---- MFMA compute (operand-swapped: D rows = oc, cols = w) ---------------
    v16f acc[2][2];
    #pragma unroll
    for (int td = 0; td < 2; ++td)
      #pragma unroll
      for (int th = 0; th < 2; ++th)
        #pragma unroll
        for (int e = 0; e < 16; ++e) acc[td][th][e] = 0.f;

    int sj[4];
    #pragma unroll
    for (int j = 0; j < 4; ++j) sj[j] = (2 * dp - 1 + j) & 3;

    __builtin_amdgcn_s_setprio(1);
    #pragma unroll
    for (int kw = 0; kw < 3; ++kw) {
      frag a[4][4];   // patches [plane j = kd+td][row r = kh+th], rows 2q..2q+3
      #pragma unroll
      for (int j = 0; j < 4; ++j)
        #pragma unroll
        for (int r = 0; r < 4; ++r)
          a[j][r] = *(const frag*)
              &xlds[((sj[j] * 10 + 2 * q + r) * 2 + hs) * 272 + (kw + m) * 8];
      #pragma unroll
      for (int kd = 0; kd < 3; ++kd)
        #pragma unroll
        for (int kh = 0; kh < 3; ++kh) {
          frag b = *(const frag*)
              &wlds[(((kd * 3 + kh) * 3 + kw) * 2 + hs) * 256 + m * 8];
          #pragma unroll
          for (int td = 0; td < 2; ++td)
            #pragma unroll
            for (int th = 0; th < 2; ++th)
              acc[td][th] = __builtin_amdgcn_mfma_f32_32x32x16_bf16(
                  b, a[kd + td][kh + th], acc[td][th], 0, 0, 0);
        }
    }
    __builtin_amdgcn_s_setprio(0);

    if (dpi < 7) {
      __syncthreads();     // all waves' reads of the overwrite-slots done
      commit(2 * dp + 3);  // pf already landed; pack + ds_write only
    }

    // ---- pool + bias + LSE(oc) + relu + store (all in-register) --------------
    // Rows = 16 ocs per lane (hs half); cols = conv w = m. Pool d (td), h (th)
    // in-register; pool w with adjacent lane via DPP quad_perm [1,0,3,2].
    // LSE: no max-shift (|v| bounded, fp32 exp-sum safe); hs halves combined
    // with one shfl_xor(32).
    float Sh = 0.f;
    #pragma unroll
    for (int r = 0; r < 16; ++r) {
      float p = fmaxf(fmaxf(acc[0][0][r], acc[0][1][r]),
                      fmaxf(acc[1][0][r], acc[1][1][r]));
      int pi = __builtin_bit_cast(int, p);
      int qi = __builtin_amdgcn_update_dpp(pi, pi, 0xB1, 0xF, 0xF, false);
      float pw2 = fmaxf(p, __builtin_bit_cast(float, qi));
      Sh += __expf(pw2 + bias_r[r]);
    }
    float S = Sh + __shfl_xor(Sh, 32, 64);
    if (hs == 0 && (m & 1) == 0) {
      float r = fmaxf(__logf(S), 0.f);
      out[((n * 16 + dp) * 32 + 4 * hpt + q) * 32 + 16 * wt + (m >> 1)] = r;
    }

    if (dpi < 7) __syncthreads();   // commits visible before next MFMA reads
  }
}

extern "C" void kernel_launch(void* const* d_in, const int* in_sizes, int n_in,
                              void* d_out, int out_size, void* d_ws, size_t ws_size,
                              hipStream_t stream) {
  const float* x = (const float*)d_in[0];
  const float* w = (const float*)d_in[1];
  const float* b = (const float*)d_in[2];
  float* out = (float*)d_out;
  conv_fused<<<dim3(2, 8, 32), dim3(256), 0, stream>>>(x, w, b, out);
}

// Round 10
// 227.215 us; speedup vs baseline: 1.0118x; 1.0118x over previous
//
#include <hip/hip_runtime.h>
#include <hip/hip_bf16.h>
#include <math.h>

#define N_   16
#define CIN  16
#define D_   32
#define H_   64
#define W_   64
#define COUT 32

#define DHW_ (D_ * H_ * W_)
#define HW_  (H_ * W_)

using frag  = __attribute__((ext_vector_type(8))) short;   // 8 bf16 = 4 VGPRs
using v16f  = __attribute__((ext_vector_type(16))) float;  // MFMA 32x32 accum

static __device__ __forceinline__ unsigned short f2bf(float f) {
  union { float f; unsigned u; } a; a.f = f;
  unsigned u = a.u;
  unsigned r = (u + 0x7fffu + ((u >> 16) & 1u)) >> 16;   // RNE
  return (unsigned short)r;
}
// Packed f32x2 -> bf16x2 (RNE), single HW instruction.
static __device__ __forceinline__ unsigned pack2(float lo, float hi) {
  unsigned r;
  asm("v_cvt_pk_bf16_f32 %0, %1, %2" : "=v"(r) : "v"(lo), "v"(hi));
  return r;
}

// Single fused kernel: conv3d(16->32,k3,p1) + bias + maxpool2^3 + LSE(ch) + relu.
// Block = 4 waves. Grid (wt=2, hpt=8, z=32: n=z>>1, dphalf=z&1).
// R9 vs R8 (96.3us, VGPR=108 PROVED sched_barrier did NOT stop the sinking):
//  - issue() now uses asm volatile global_load_dword (SGPR base + 32b voffset).
//    Volatile asm cannot be sunk past the barrier; its 48 dest VGPRs are live
//    across the MFMA block, so the gather latency hides under compute.
//  - commit() starts with s_waitcnt vmcnt(0) + sched_barrier(0) (rule #18:
//    compiler doesn't track inline-asm loads; the fence stops pack hoisting).
//  - R8's post-issue sched_barrier dropped (measured no-op).
// Verification bit: VGPR_Count must jump to ~180-210.
__global__ __launch_bounds__(256, 2)
void conv_fused(const float* __restrict__ x,
                const float* __restrict__ w,
                const float* __restrict__ bias,
                float* __restrict__ out) {
  // [4 slot][10 row][2 ichalf][34 wslot][8 ic]  = 21760 shorts = 43520 B
  __shared__ __hip_bfloat16 xlds[4 * 10 * 2 * 34 * 8];
  // [27 tap][2 ichalf][32 oc][8 ic]             = 13824 shorts = 27648 B
  __shared__ __hip_bfloat16 wlds[27 * 2 * 32 * 8];

  const int tid = threadIdx.x;
  const int lane = tid & 63;
  const int q = tid >> 6;            // wave id
  const int m = lane & 31;
  const int hs = lane >> 5;
  const int wt = blockIdx.x;         // 0..1
  const int hpt = blockIdx.y;        // 0..7
  const int n = blockIdx.z >> 1;
  const int dphalf = blockIdx.z & 1;

  // ---- stage weights: wlds[tap][ic>>3][oc][ic&7] <- bf16(w[oc][ic][tap]) ----
  for (int i = tid; i < 27 * 32 * 16; i += 256) {
    int ic = i & 15;
    int t2 = i >> 4;
    int oc = t2 & 31;
    int tap = t2 >> 5;
    wlds[((tap * 2 + (ic >> 3)) * 32 + oc) * 8 + (ic & 7)] =
        __hip_bfloat16(__hip_bfloat16_raw{f2bf(w[(oc * 16 + ic) * 27 + tap])});
  }

  // Per-lane bias for the 16 accum rows (row/oc = (r&3)+8*(r>>2)+4*hs).
  float bias_r[16];
  #pragma unroll
  for (int r = 0; r < 16; ++r)
    bias_r[r] = bias[(r & 3) + 8 * (r >> 2) + 4 * hs];

  const int h0 = 8 * hpt - 1;
  const int w0g = wt * 32 - 1;
  const float* xn = x + (size_t)n * CIN * DHW_;

  // 8 uniform channel-base pointers -> SGPR pairs.
  const float* xj[8];
  #pragma unroll
  for (int j = 0; j < 8; ++j) xj[j] = xn + (size_t)j * DHW_;

  // ---- per-thread staging descriptors (decode hoisted out of the dpi loop) --
  // Task t = tid + 256k, t in [0,1360): ru = t/68, sub = t%68,
  // s = sub>>1 (w-slot 0..33), half = sub&1 (ic half), go = (ru>=10),
  // rr = ru%10 (LDS row). Only k=5 can be inactive (t>=1360 <=> tid>=80).
  int goffw[6];   // global word offset, excluding the g-plane term
  int ldsoB[6];   // LDS byte offset within one plane slot
  int go6[6];     // plane offset within the staged pair (0/1)
  bool vhw6[6];   // active && h,w in bounds (g checked per call)
  #pragma unroll
  for (int k = 0; k < 6; ++k) {
    int t = tid + 256 * k;
    int ru = t / 68;
    int sub = t - ru * 68;
    int go = (ru >= 10) ? 1 : 0;
    int rr = ru - 10 * go;
    int s = sub >> 1, half = sub & 1;
    int h = h0 + rr, gw = w0g + s;
    go6[k] = go;
    vhw6[k] = (t < 1360) && ((unsigned)h < (unsigned)H_) &&
              ((unsigned)gw < (unsigned)W_);
    // [row][half][wslot][8ic] bf16 -> byte = ((rr*2 + half)*34 + s)*16
    ldsoB[k] = ((rr * 2 + half) * 34 + s) * 16;
    goffw[k] = half * 8 * DHW_ + h * W_ + gw;
  }
  const bool act5 = (tid < 80);   // k=5 task-active mask (k<5 always active)

  // Immediate staging of planes {g0, g0+1} (prologue): load+pack+write.
  auto stage_now = [&](int g0) {
    #pragma unroll
    for (int k = 0; k < 6; ++k) {
      int g = g0 + go6[k];
      bool v = vhw6[k] && ((unsigned)g < (unsigned)D_);
      unsigned offw = v ? (unsigned)(goffw[k] + g * HW_) : 0u;  // clamp: in-bounds
      float f[8];
      #pragma unroll
      for (int j = 0; j < 8; ++j) f[j] = xj[j][offw];
      uint4 val;
      val.x = v ? pack2(f[0], f[1]) : 0u;
      val.y = v ? pack2(f[2], f[3]) : 0u;
      val.z = v ? pack2(f[4], f[5]) : 0u;
      val.w = v ? pack2(f[6], f[7]) : 0u;
      if (k < 5 || act5)
        *(uint4*)((char*)xlds + ((g & 3) * 10880 + ldsoB[k])) = val;
    }
  };

  float pf[6][8];   // prefetch buffer, live across the MFMA block (asm-pinned)

  // Compiler-opaque gather: volatile asm global_load_dword cannot be sunk
  // past the barrier into commit(); dest VGPRs stay allocated in-flight.
  auto issue = [&](int g0) {
    #pragma unroll
    for (int k = 0; k < 6; ++k) {
      int g = g0 + go6[k];
      bool v = vhw6[k] && ((unsigned)g < (unsigned)D_);
      unsigned offB = v ? (unsigned)(goffw[k] + g * HW_) * 4u : 0u;  // clamped
      #pragma unroll
      for (int j = 0; j < 8; ++j)
        asm volatile("global_load_dword %0, %1, %2"
                     : "=v"(pf[k][j])
                     : "v"(offB), "s"(xj[j]));
    }
  };

  auto commit = [&](int g0) {
    // Inline-asm loads are invisible to the compiler's waitcnt insertion:
    // drain them explicitly, then fence (rule #18) so the packs below are
    // not hoisted above the wait.
    asm volatile("s_waitcnt vmcnt(0)" ::: "memory");
    __builtin_amdgcn_sched_barrier(0);
    #pragma unroll
    for (int k = 0; k < 6; ++k) {
      int g = g0 + go6[k];
      bool v = vhw6[k] && ((unsigned)g < (unsigned)D_);
      uint4 val;
      val.x = v ? pack2(pf[k][0], pf[k][1]) : 0u;
      val.y = v ? pack2(pf[k][2], pf[k][3]) : 0u;
      val.z = v ? pack2(pf[k][4], pf[k][5]) : 0u;
      val.w = v ? pack2(pf[k][6], pf[k][7]) : 0u;
      if (k < 5 || act5)
        *(uint4*)((char*)xlds + ((g & 3) * 10880 + ldsoB[k])) = val;
    }
  };

  const int dp0 = dphalf * 8;
  stage_now(2 * dp0 - 1);
  stage_now(2 * dp0 + 1);
  __syncthreads();   // prologue staging + weights visible

  for (int dpi = 0; dpi < 8; ++dpi) {
    const int dp = dp0 + dpi;

    if (dpi < 7) issue(2 * dp + 3);   // asm loads: genuinely in flight now

    // ---- MFMA compute (operand-swapped: D rows = oc, cols = w) ---------------
    v16f acc[2][2];
    #pragma unroll
    for (int td = 0; td < 2; ++td)
      #pragma unroll
      for (int th = 0; th < 2; ++th)
        #pragma unroll
        for (int e = 0; e < 16; ++e) acc[td][th][e] = 0.f;

    int sj[4];
    #pragma unroll
    for (int j = 0; j < 4; ++j) sj[j] = (2 * dp - 1 + j) & 3;

    __builtin_amdgcn_s_setprio(1);
    #pragma unroll
    for (int kw = 0; kw < 3; ++kw) {
      frag a[4][4];   // patches [plane j = kd+td][row r = kh+th], rows 2q..2q+3
      #pragma unroll
      for (int j = 0; j < 4; ++j)
        #pragma unroll
        for (int r = 0; r < 4; ++r)
          a[j][r] = *(const frag*)
              &xlds[((sj[j] * 10 + 2 * q + r) * 2 + hs) * 272 + (kw + m) * 8];
      #pragma unroll
      for (int kd = 0; kd < 3; ++kd)
        #pragma unroll
        for (int kh = 0; kh < 3; ++kh) {
          frag b = *(const frag*)
              &wlds[(((kd * 3 + kh) * 3 + kw) * 2 + hs) * 256 + m * 8];
          #pragma unroll
          for (int td = 0; td < 2; ++td)
            #pragma unroll
            for (int th = 0; th < 2; ++th)
              acc[td][th] = __builtin_amdgcn_mfma_f32_32x32x16_bf16(
                  b, a[kd + td][kh + th], acc[td][th], 0, 0, 0);
        }
    }
    __builtin_amdgcn_s_setprio(0);

    if (dpi < 7) {
      __syncthreads();     // all waves' reads of the overwrite-slots done
      commit(2 * dp + 3);  // vmcnt(0) drain; pack + ds_write
    }

    // ---- pool + bias + LSE(oc) + relu + store (all in-register) --------------
    // Rows = 16 ocs per lane (hs half); cols = conv w = m. Pool d (td), h (th)
    // in-register; pool w with adjacent lane via DPP quad_perm [1,0,3,2].
    // LSE: no max-shift (|v| bounded, fp32 exp-sum safe); hs halves combined
    // with one shfl_xor(32).
    float Sh = 0.f;
    #pragma unroll
    for (int r = 0; r < 16; ++r) {
      float p = fmaxf(fmaxf(acc[0][0][r], acc[0][1][r]),
                      fmaxf(acc[1][0][r], acc[1][1][r]));
      int pi = __builtin_bit_cast(int, p);
      int qi = __builtin_amdgcn_update_dpp(pi, pi, 0xB1, 0xF, 0xF, false);
      float pw2 = fmaxf(p, __builtin_bit_cast(float, qi));
      Sh += __expf(pw2 + bias_r[r]);
    }
    float S = Sh + __shfl_xor(Sh, 32, 64);
    if (hs == 0 && (m & 1) == 0) {
      float r = fmaxf(__logf(S), 0.f);
      out[((n * 16 + dp) * 32 + 4 * hpt + q) * 32 + 16 * wt + (m >> 1)] = r;
    }

    if (dpi < 7) __syncthreads();   // commits visible before next MFMA reads
  }
}

extern "C" void kernel_launch(void* const* d_in, const int* in_sizes, int n_in,
                              void* d_out, int out_size, void* d_ws, size_t ws_size,
                              hipStream_t stream) {
  const float* x = (const float*)d_in[0];
  const float* w = (const float*)d_in[1];
  const float* b = (const float*)d_in[2];
  float* out = (float*)d_out;
  conv_fused<<<dim3(2, 8, 32), dim3(256), 0, stream>>>(x, w, b, out);
}